// Round 5
// baseline (712.279 us; speedup 1.0000x reference)
//
#include <hip/hip_runtime.h>

// ---------------------------------------------------------------------------
// MMoE: B=8192, D_IN=1024, E=8, T=4, H1=1024, H2=512, H3=256
// bf16 MFMA GEMMs. Round-5 structure: pipe-cycle minimization.
//   Wall ~= sum(MFMA + LDS + VALU) cycles (R3/R4 counter fit), so:
//   - A operand: DIRECT global->register loads (compiler emits fine-grained
//     vmcnt(N) for reg loads - the hipBLASLt pattern). No LDS for A.
//   - B operand: LDS-staged, double-buffered, prefetch issued AFTER barrier.
//   - A-loads issue BEFORE B-prefetch each iter: vmcnt retires in-order, so
//     A's MFMA wait must not queue behind the fresh B prefetch.
// Tile 256x128 (4 waves, wave tile 128x64), BK=64, 16x16x32 mfma,
// XOR-swizzled B LDS (0 bank conflicts). fp32 gating, fused bias+relu.
// ---------------------------------------------------------------------------

#define B_ROWS 8192
#define D_IN   1024
#define NEXP   8
#define NTASK  4
#define H1     1024
#define H2     512
#define H3     256

typedef __attribute__((ext_vector_type(8))) short bf16x8;
typedef __attribute__((ext_vector_type(4))) float f32x4;

__device__ __forceinline__ unsigned short f2bf(float f) {
    union { float f; unsigned int u; } x; x.f = f;
    unsigned int r = x.u + 0x7fffu + ((x.u >> 16) & 1u);  // RNE
    return (unsigned short)(r >> 16);
}
__device__ __forceinline__ float bf2f(unsigned short u) {
    union { unsigned int u; float f; } x; x.u = ((unsigned int)u) << 16;
    return x.f;
}

__device__ __forceinline__ void gload_lds16(const void* gptr, void* lptr) {
    __builtin_amdgcn_global_load_lds(
        (__attribute__((address_space(1))) void*)gptr,
        (__attribute__((address_space(3))) void*)lptr,
        16, 0, 0);
}

// ---------------------------------------------------------------------------
// x fp32 -> bf16, 4 elements/thread
// ---------------------------------------------------------------------------
struct __align__(8) us4 { unsigned short x, y, z, w; };

__global__ void convert_x_kernel(const float* __restrict__ x,
                                 unsigned short* __restrict__ xb) {
    int i = blockIdx.x * blockDim.x + threadIdx.x;
    float4 v = ((const float4*)x)[i];
    us4 o;
    o.x = f2bf(v.x); o.y = f2bf(v.y); o.z = f2bf(v.z); o.w = f2bf(v.w);
    ((us4*)xb)[i] = o;
}

// ---------------------------------------------------------------------------
// W [E][K][N] fp32 -> Wt [E][N][K] bf16 (32x32 LDS tile transpose)
// ---------------------------------------------------------------------------
__global__ void transpose_convert_kernel(const float* __restrict__ W,
                                         unsigned short* __restrict__ Wt,
                                         int K, int N) {
    __shared__ float tile[32][33];
    const int e = blockIdx.z;
    const float* We = W + (size_t)e * K * N;
    unsigned short* Wte = Wt + (size_t)e * K * N;
    const int k0 = blockIdx.x * 32, n0 = blockIdx.y * 32;
    const int tx = threadIdx.x, ty = threadIdx.y;  // (32, 8)
#pragma unroll
    for (int i = 0; i < 4; ++i)
        tile[ty + i * 8][tx] = We[(size_t)(k0 + ty + i * 8) * N + n0 + tx];
    __syncthreads();
#pragma unroll
    for (int i = 0; i < 4; ++i)
        Wte[(size_t)(n0 + ty + i * 8) * K + k0 + tx] = f2bf(tile[tx][ty + i * 8]);
}

// ---------------------------------------------------------------------------
// GEMM: C[e] = relu(A[e] @ Bt[e]^T + bias[e]) ; all bf16, acc fp32
// A: [M,K] rm (per-expert stride Aes elems), Bt: [N,K] rm, C: [M,N] rm bf16
// block = 256 (4 waves, 2x2), tile 256x128 (M x N), wave tile 128x64, BK=64.
// A: direct global->reg (per-lane addr = MFMA A-operand layout;
//    16 rows x 64 B contiguous per global_load_dwordx4 - fine coalescing).
// B: LDS dbuf. Rows are 8 chunks of 16B; chunk c of row r holds global chunk
// c^(r&7) (XOR swizzle): ds_read_b128 fragment reads hit all 32 banks.
// M % 256 == 0, N % 128 == 0, K % 64 == 0.
// ---------------------------------------------------------------------------
__global__ __launch_bounds__(256, 2) void gemm_bias_relu_kernel(
    const unsigned short* __restrict__ A, long long Aes,
    const unsigned short* __restrict__ Bt, long long Bes,
    const float* __restrict__ bias, long long bias_es,
    unsigned short* __restrict__ C, long long Ces,
    int M, int N, int K) {
    __shared__ __align__(16) unsigned short sB[2][128 * 64];

    const int tid  = threadIdx.x;
    const int lane = tid & 63;
    const int w    = tid >> 6;       // wave 0..3
    const int wr   = w >> 1, wc = w & 1;
    const int quad = lane >> 4, l15 = lane & 15;
    const int r8   = lane >> 3;      // staging row-in-octet 0..7
    const int c8   = lane & 7;       // staging 16B-chunk 0..7
    const int gchunk = c8 ^ r8;      // XOR-swizzled global chunk to fetch

    const int e  = blockIdx.z;
    const int m0 = blockIdx.x * 256;
    const int n0 = blockIdx.y * 128;

    A    += (size_t)e * Aes;
    Bt   += (size_t)e * Bes;
    bias += (size_t)e * bias_es;
    C    += (size_t)e * Ces;

    // A direct-load base: fragment i, s-step s, iter it reads per-lane 16 B at
    // row (m0 + wr*128 + i*16 + l15), k = it*64 + s*32 + quad*8
    const unsigned short* Arow = A + (size_t)(m0 + wr * 128 + l15) * K + quad * 8;

    // B staging: wave w covers rows [w*32, w*32+32)
    const unsigned short* Bbase = Bt + (size_t)(n0 + w * 32 + r8) * K + gchunk * 8;
    unsigned short* sBw = &sB[0][(w * 32 + r8) * 64 + c8 * 8];

    f32x4 acc[8][4] = {};
    const int swz = l15 & 7;         // read-side XOR (row&7 of fragment rows)
    const int niter = K >> 6;

    // prologue: stage B tile 0 into buffer 0
#pragma unroll
    for (int q = 0; q < 4; ++q)
        gload_lds16(Bbase + (size_t)(q * 8) * K, sBw + q * 8 * 64);

    for (int it = 0; it < niter; ++it) {
        __syncthreads();  // drains B tile-it (in flight for one full phase)

        // 1) A fragments for this iter: 16 independent reg loads, issued FIRST
        bf16x8 af[2][8];
        const size_t ka = (size_t)it * 64;
#pragma unroll
        for (int s = 0; s < 2; ++s)
#pragma unroll
            for (int i = 0; i < 8; ++i)
                af[s][i] = *(const bf16x8*)(Arow + (size_t)(i * 16) * K + ka + s * 32);

        // 2) B prefetch for tile it+1 (drained at NEXT barrier)
        if (it + 1 < niter) {
            const int buf = (it + 1) & 1;
            const size_t koff = (size_t)(it + 1) << 6;
#pragma unroll
            for (int q = 0; q < 4; ++q)
                gload_lds16(Bbase + (size_t)(q * 8) * K + koff,
                            sBw + buf * (128 * 64) + q * 8 * 64);
        }

        // 3) compute on B buffer it&1
        const unsigned short* b_ = sB[it & 1];
#pragma unroll
        for (int s = 0; s < 2; ++s) {
            const int cs = ((s * 4 + quad) ^ swz) * 8;  // swizzled k-chunk
            bf16x8 bfv[4];
#pragma unroll
            for (int j = 0; j < 4; ++j)
                bfv[j] = *(const bf16x8*)&b_[(wc * 64 + j * 16 + l15) * 64 + cs];
#pragma unroll
            for (int i = 0; i < 8; ++i)
#pragma unroll
                for (int j = 0; j < 4; ++j)
                    acc[i][j] = __builtin_amdgcn_mfma_f32_16x16x32_bf16(
                        af[s][i], bfv[j], acc[i][j], 0, 0, 0);
        }
    }

    // epilogue: C/D layout col=lane&15, row=quad*4+reg
#pragma unroll
    for (int j = 0; j < 4; ++j) {
        const int col = n0 + wc * 64 + j * 16 + l15;
        const float bv = bias[col];
#pragma unroll
        for (int i = 0; i < 8; ++i) {
#pragma unroll
            for (int r = 0; r < 4; ++r) {
                const int row = m0 + wr * 128 + i * 16 + quad * 4 + r;
                float v = acc[i][j][r] + bv;
                v = v > 0.f ? v : 0.f;
                C[(size_t)row * N + col] = f2bf(v);
            }
        }
    }
}

// ---------------------------------------------------------------------------
// gates: logits = x @ gate_w  [B, 32]; softmax over e within each task group
// block 256 = 8 rows x 32 outputs; output gates[b][t*8+e]
// ---------------------------------------------------------------------------
__global__ void gates_kernel(const float* __restrict__ x,
                             const float* __restrict__ gw,
                             float* __restrict__ gates) {
    const int tid = threadIdx.x;
    const int o = tid & 31;          // t*8 + e
    const int r = tid >> 5;          // 0..7
    const int b = blockIdx.x * 8 + r;
    const float* xr = x + (size_t)b * D_IN;
    float acc = 0.f;
    for (int k = 0; k < D_IN; k += 4) {
        float4 xv = *(const float4*)&xr[k];
        acc += xv.x * gw[(k + 0) * 32 + o];
        acc += xv.y * gw[(k + 1) * 32 + o];
        acc += xv.z * gw[(k + 2) * 32 + o];
        acc += xv.w * gw[(k + 3) * 32 + o];
    }
    // softmax over the 8 experts (lanes o = t*8 + e, e in low 3 bits)
    float m = acc;
    m = fmaxf(m, __shfl_xor(m, 1));
    m = fmaxf(m, __shfl_xor(m, 2));
    m = fmaxf(m, __shfl_xor(m, 4));
    float ex = __expf(acc - m);
    float s = ex;
    s += __shfl_xor(s, 1);
    s += __shfl_xor(s, 2);
    s += __shfl_xor(s, 4);
    gates[(size_t)b * 32 + o] = ex / s;
}

// ---------------------------------------------------------------------------
// combine: out[t][b][d] = sum_e h3[e][b][d] * g[b][t*8+e]
// one block per b, 256 threads = d
// ---------------------------------------------------------------------------
__global__ void combine_kernel(const unsigned short* __restrict__ h3,
                               const float* __restrict__ gates,
                               float* __restrict__ out) {
    __shared__ float g[32];
    const int b = blockIdx.x;
    const int d = threadIdx.x;
    if (d < 32) g[d] = gates[(size_t)b * 32 + d];
    __syncthreads();
    float acc[NTASK] = {0.f, 0.f, 0.f, 0.f};
#pragma unroll
    for (int e = 0; e < NEXP; ++e) {
        const float h = bf2f(h3[((size_t)e * B_ROWS + b) * H3 + d]);
#pragma unroll
        for (int t = 0; t < NTASK; ++t) acc[t] += h * g[t * 8 + e];
    }
#pragma unroll
    for (int t = 0; t < NTASK; ++t)
        out[((size_t)t * B_ROWS + b) * H3 + d] = acc[t];
}

// ---------------------------------------------------------------------------
// workspace layout (bytes)
// ---------------------------------------------------------------------------
#define OFF_XBF 0u                          // 8192*1024*2      = 16,777,216
#define OFF_W1T 16777216u                   // 8*1024*1024*2    = 16,777,216
#define OFF_W2T 33554432u                   // 8*512*1024*2     =  8,388,608
#define OFF_W3T 41943040u                   // 8*256*512*2      =  2,097,152
#define OFF_G   44040192u                   // 8192*32*4        =  1,048,576
#define OFF_H1  45088768u                   // 8*8192*1024*2    = 134,217,728
#define OFF_H2  179306496u                  // 8*8192*512*2     = 67,108,864
#define OFF_H3  45088768u                   // aliases h1 (h1 dead after L2)
// total required: 246,415,360 bytes

extern "C" void kernel_launch(void* const* d_in, const int* in_sizes, int n_in,
                              void* d_out, int out_size, void* d_ws, size_t ws_size,
                              hipStream_t stream) {
    const float* x  = (const float*)d_in[0];
    const float* W1 = (const float*)d_in[1];
    const float* b1 = (const float*)d_in[2];
    const float* W2 = (const float*)d_in[3];
    const float* b2 = (const float*)d_in[4];
    const float* W3 = (const float*)d_in[5];
    const float* b3 = (const float*)d_in[6];
    const float* gw = (const float*)d_in[7];
    float* out = (float*)d_out;
    char* ws = (char*)d_ws;

    unsigned short* xbf = (unsigned short*)(ws + OFF_XBF);
    unsigned short* w1t = (unsigned short*)(ws + OFF_W1T);
    unsigned short* w2t = (unsigned short*)(ws + OFF_W2T);
    unsigned short* w3t = (unsigned short*)(ws + OFF_W3T);
    float*          gts = (float*)(ws + OFF_G);
    unsigned short* h1  = (unsigned short*)(ws + OFF_H1);
    unsigned short* h2  = (unsigned short*)(ws + OFF_H2);
    unsigned short* h3  = (unsigned short*)(ws + OFF_H3);

    // input conversions
    convert_x_kernel<<<dim3((B_ROWS * D_IN) / 4 / 256), dim3(256), 0, stream>>>(x, xbf);
    transpose_convert_kernel<<<dim3(D_IN / 32, H1 / 32, NEXP), dim3(32, 8), 0, stream>>>(W1, w1t, D_IN, H1);
    transpose_convert_kernel<<<dim3(H1 / 32, H2 / 32, NEXP), dim3(32, 8), 0, stream>>>(W2, w2t, H1, H2);
    transpose_convert_kernel<<<dim3(H2 / 32, H3 / 32, NEXP), dim3(32, 8), 0, stream>>>(W3, w3t, H2, H3);

    // gates (fp32, independent of expert path)
    gates_kernel<<<dim3(B_ROWS / 8), dim3(256), 0, stream>>>(x, gw, gts);

    // expert MLP layers
    gemm_bias_relu_kernel<<<dim3(B_ROWS / 256, H1 / 128, NEXP), dim3(256), 0, stream>>>(
        xbf, 0LL,
        w1t, (long long)H1 * D_IN,
        b1, (long long)H1,
        h1, (long long)B_ROWS * H1,
        B_ROWS, H1, D_IN);
    gemm_bias_relu_kernel<<<dim3(B_ROWS / 256, H2 / 128, NEXP), dim3(256), 0, stream>>>(
        h1, (long long)B_ROWS * H1,
        w2t, (long long)H2 * H1,
        b2, (long long)H2,
        h2, (long long)B_ROWS * H2,
        B_ROWS, H2, H1);
    gemm_bias_relu_kernel<<<dim3(B_ROWS / 256, H3 / 128, NEXP), dim3(256), 0, stream>>>(
        h2, (long long)B_ROWS * H2,
        w3t, (long long)H3 * H2,
        b3, (long long)H3,
        h3, (long long)B_ROWS * H3,
        B_ROWS, H3, H2);

    // gated combine
    combine_kernel<<<dim3(B_ROWS), dim3(256), 0, stream>>>(h3, gts, out);
}

// Round 6
// 454.175 us; speedup vs baseline: 1.5683x; 1.5683x over previous
//
#include <hip/hip_runtime.h>

// ---------------------------------------------------------------------------
// MMoE: B=8192, D_IN=1024, E=8, T=4, H1=1024, H2=512, H3=256
// Round-6: occupancy experiment. GEMM tile 128x128 (4 waves, 64x64/wave),
// BK=64, single-buffered 32KB LDS, XOR swizzle (0 conflicts),
// __launch_bounds__(256,4) -> <=128 VGPR/wave -> 4 blocks/CU (16 waves/CU).
// Hypothesis: all prior rounds ran 2 waves/SIMD (acc-register bound); pipes
// couldn't overlap (no pipe >40% busy). 2x TLP should lift MfmaUtil.
// A/B staged via global_load_lds w=16 (R5 showed direct reg loads fragment
// into 16x64B scatter - 2x regression). fp32 gating fused with x->bf16.
// ---------------------------------------------------------------------------

#define B_ROWS 8192
#define D_IN   1024
#define NEXP   8
#define NTASK  4
#define H1     1024
#define H2     512
#define H3     256

typedef __attribute__((ext_vector_type(8))) short bf16x8;
typedef __attribute__((ext_vector_type(4))) float f32x4;

__device__ __forceinline__ unsigned short f2bf(float f) {
    union { float f; unsigned int u; } x; x.f = f;
    unsigned int r = x.u + 0x7fffu + ((x.u >> 16) & 1u);  // RNE
    return (unsigned short)(r >> 16);
}
__device__ __forceinline__ float bf2f(unsigned short u) {
    union { unsigned int u; float f; } x; x.u = ((unsigned int)u) << 16;
    return x.f;
}

__device__ __forceinline__ void gload_lds16(const void* gptr, void* lptr) {
    __builtin_amdgcn_global_load_lds(
        (__attribute__((address_space(1))) void*)gptr,
        (__attribute__((address_space(3))) void*)lptr,
        16, 0, 0);
}

struct __align__(8) us4 { unsigned short x, y, z, w; };

// ---------------------------------------------------------------------------
// W [E][K][N] fp32 -> Wt [E][N][K] bf16 (32x32 LDS tile transpose)
// ---------------------------------------------------------------------------
__global__ void transpose_convert_kernel(const float* __restrict__ W,
                                         unsigned short* __restrict__ Wt,
                                         int K, int N) {
    __shared__ float tile[32][33];
    const int e = blockIdx.z;
    const float* We = W + (size_t)e * K * N;
    unsigned short* Wte = Wt + (size_t)e * K * N;
    const int k0 = blockIdx.x * 32, n0 = blockIdx.y * 32;
    const int tx = threadIdx.x, ty = threadIdx.y;  // (32, 8)
#pragma unroll
    for (int i = 0; i < 4; ++i)
        tile[ty + i * 8][tx] = We[(size_t)(k0 + ty + i * 8) * N + n0 + tx];
    __syncthreads();
#pragma unroll
    for (int i = 0; i < 4; ++i)
        Wte[(size_t)(n0 + ty + i * 8) * K + k0 + tx] = f2bf(tile[tx][ty + i * 8]);
}

// ---------------------------------------------------------------------------
// GEMM: C[e] = relu(A[e] @ Bt[e]^T + bias[e]) ; all bf16, acc fp32
// A: [M,K] rm (per-expert stride Aes elems), Bt: [N,K] rm, C: [M,N] rm bf16
// block = 256 (4 waves, 2x2), tile 128x128, BK=64, single-buffered.
// LDS rows are 8 chunks of 16B; chunk c of row r holds global chunk c^(r&7)
// (XOR swizzle): consecutive-8-lane groups of each ds_read_b128 hit all 8
// bank-quads -> 0 conflicts. M,N % 128 == 0, K % 64 == 0.
// launch_bounds(256,4): 4 blocks/CU -> 16 waves/CU for latency hiding.
// ---------------------------------------------------------------------------
__global__ __launch_bounds__(256, 4) void gemm_bias_relu_kernel(
    const unsigned short* __restrict__ A, long long Aes,
    const unsigned short* __restrict__ Bt, long long Bes,
    const float* __restrict__ bias, long long bias_es,
    unsigned short* __restrict__ C, long long Ces,
    int M, int N, int K) {
    __shared__ __align__(16) unsigned short sA[128 * 64];
    __shared__ __align__(16) unsigned short sB[128 * 64];

    const int tid  = threadIdx.x;
    const int lane = tid & 63;
    const int w    = tid >> 6;       // wave 0..3
    const int wr   = w >> 1, wc = w & 1;
    const int quad = lane >> 4, l15 = lane & 15;
    const int r8   = lane >> 3;      // staging row-in-octet 0..7
    const int c8   = lane & 7;       // staging 16B-chunk 0..7
    const int gchunk = c8 ^ r8;      // XOR-swizzled global chunk to fetch

    const int e  = blockIdx.z;
    const int m0 = blockIdx.x * 128;
    const int n0 = blockIdx.y * 128;

    A    += (size_t)e * Aes;
    Bt   += (size_t)e * Bes;
    bias += (size_t)e * bias_es;
    C    += (size_t)e * Ces;

    // staging: wave w covers A rows [w*32,w*32+32) and B rows [w*32,w*32+32)
    const unsigned short* Abase = A + (size_t)(m0 + w * 32 + r8) * K + gchunk * 8;
    const unsigned short* Bbase = Bt + (size_t)(n0 + w * 32 + r8) * K + gchunk * 8;
    unsigned short* sAw = &sA[(w * 32 + r8) * 64 + c8 * 8];
    unsigned short* sBw = &sB[(w * 32 + r8) * 64 + c8 * 8];

    f32x4 acc[4][4] = {};
    const int swz = l15 & 7;         // read-side XOR (row&7 of fragment rows)

    for (int k0 = 0; k0 < K; k0 += 64) {
#pragma unroll
        for (int q = 0; q < 4; ++q) {
            gload_lds16(Abase + (size_t)(q * 8) * K + k0, sAw + q * 8 * 64);
            gload_lds16(Bbase + (size_t)(q * 8) * K + k0, sBw + q * 8 * 64);
        }
        __syncthreads();

#pragma unroll
        for (int s = 0; s < 2; ++s) {
            const int cs = ((s * 4 + quad) ^ swz) * 8;  // swizzled k-chunk
            bf16x8 af[4], bfv[4];
#pragma unroll
            for (int i = 0; i < 4; ++i)
                af[i] = *(const bf16x8*)&sA[(wr * 64 + i * 16 + l15) * 64 + cs];
#pragma unroll
            for (int j = 0; j < 4; ++j)
                bfv[j] = *(const bf16x8*)&sB[(wc * 64 + j * 16 + l15) * 64 + cs];
#pragma unroll
            for (int i = 0; i < 4; ++i)
#pragma unroll
                for (int j = 0; j < 4; ++j)
                    acc[i][j] = __builtin_amdgcn_mfma_f32_16x16x32_bf16(
                        af[i], bfv[j], acc[i][j], 0, 0, 0);
        }
        __syncthreads();
    }

    // epilogue: C/D layout col=lane&15, row=quad*4+reg
#pragma unroll
    for (int j = 0; j < 4; ++j) {
        const int col = n0 + wc * 64 + j * 16 + l15;
        const float bv = bias[col];
#pragma unroll
        for (int i = 0; i < 4; ++i) {
#pragma unroll
            for (int r = 0; r < 4; ++r) {
                const int row = m0 + wr * 64 + i * 16 + quad * 4 + r;
                float v = acc[i][j][r] + bv;
                v = v > 0.f ? v : 0.f;
                C[(size_t)row * N + col] = f2bf(v);
            }
        }
    }
}

// ---------------------------------------------------------------------------
// gates + x->bf16 convert fused.
// block 256 = 8 rows x 32 outputs; also converts this block's 8 x-rows
// (8192 floats, 32 per thread) to bf16.
// ---------------------------------------------------------------------------
__global__ void gates_convert_kernel(const float* __restrict__ x,
                                     const float* __restrict__ gw,
                                     float* __restrict__ gates,
                                     unsigned short* __restrict__ xb) {
    const int tid = threadIdx.x;
    // --- convert: this block's slab = rows [blockIdx.x*8, +8) = 8192 floats
    const size_t base = (size_t)blockIdx.x * 8192 + (size_t)tid * 32;
#pragma unroll
    for (int i = 0; i < 8; ++i) {
        float4 v = *(const float4*)&x[base + i * 4];
        us4 o4;
        o4.x = f2bf(v.x); o4.y = f2bf(v.y); o4.z = f2bf(v.z); o4.w = f2bf(v.w);
        ((us4*)xb)[base / 4 + i] = o4;
    }
    // --- gates
    const int o = tid & 31;          // t*8 + e
    const int r = tid >> 5;          // 0..7
    const int b = blockIdx.x * 8 + r;
    const float* xr = x + (size_t)b * D_IN;
    float acc = 0.f;
    for (int k = 0; k < D_IN; k += 4) {
        float4 xv = *(const float4*)&xr[k];
        acc += xv.x * gw[(k + 0) * 32 + o];
        acc += xv.y * gw[(k + 1) * 32 + o];
        acc += xv.z * gw[(k + 2) * 32 + o];
        acc += xv.w * gw[(k + 3) * 32 + o];
    }
    // softmax over the 8 experts (lanes o = t*8 + e, e in low 3 bits)
    float m = acc;
    m = fmaxf(m, __shfl_xor(m, 1));
    m = fmaxf(m, __shfl_xor(m, 2));
    m = fmaxf(m, __shfl_xor(m, 4));
    float ex = __expf(acc - m);
    float s = ex;
    s += __shfl_xor(s, 1);
    s += __shfl_xor(s, 2);
    s += __shfl_xor(s, 4);
    gates[(size_t)b * 32 + o] = ex / s;
}

// ---------------------------------------------------------------------------
// combine: out[t][b][d] = sum_e h3[e][b][d] * g[b][t*8+e]
// one block per b, 256 threads = d
// ---------------------------------------------------------------------------
__global__ void combine_kernel(const unsigned short* __restrict__ h3,
                               const float* __restrict__ gates,
                               float* __restrict__ out) {
    __shared__ float g[32];
    const int b = blockIdx.x;
    const int d = threadIdx.x;
    if (d < 32) g[d] = gates[(size_t)b * 32 + d];
    __syncthreads();
    float acc[NTASK] = {0.f, 0.f, 0.f, 0.f};
#pragma unroll
    for (int e = 0; e < NEXP; ++e) {
        const float h = bf2f(h3[((size_t)e * B_ROWS + b) * H3 + d]);
#pragma unroll
        for (int t = 0; t < NTASK; ++t) acc[t] += h * g[t * 8 + e];
    }
#pragma unroll
    for (int t = 0; t < NTASK; ++t)
        out[((size_t)t * B_ROWS + b) * H3 + d] = acc[t];
}

// ---------------------------------------------------------------------------
// workspace layout (bytes)
// ---------------------------------------------------------------------------
#define OFF_XBF 0u                          // 8192*1024*2      = 16,777,216
#define OFF_W1T 16777216u                   // 8*1024*1024*2    = 16,777,216
#define OFF_W2T 33554432u                   // 8*512*1024*2     =  8,388,608
#define OFF_W3T 41943040u                   // 8*256*512*2      =  2,097,152
#define OFF_G   44040192u                   // 8192*32*4        =  1,048,576
#define OFF_H1  45088768u                   // 8*8192*1024*2    = 134,217,728
#define OFF_H2  179306496u                  // 8*8192*512*2     = 67,108,864
#define OFF_H3  45088768u                   // aliases h1 (h1 dead after L2)
// total required: 246,415,360 bytes

extern "C" void kernel_launch(void* const* d_in, const int* in_sizes, int n_in,
                              void* d_out, int out_size, void* d_ws, size_t ws_size,
                              hipStream_t stream) {
    const float* x  = (const float*)d_in[0];
    const float* W1 = (const float*)d_in[1];
    const float* b1 = (const float*)d_in[2];
    const float* W2 = (const float*)d_in[3];
    const float* b2 = (const float*)d_in[4];
    const float* W3 = (const float*)d_in[5];
    const float* b3 = (const float*)d_in[6];
    const float* gw = (const float*)d_in[7];
    float* out = (float*)d_out;
    char* ws = (char*)d_ws;

    unsigned short* xbf = (unsigned short*)(ws + OFF_XBF);
    unsigned short* w1t = (unsigned short*)(ws + OFF_W1T);
    unsigned short* w2t = (unsigned short*)(ws + OFF_W2T);
    unsigned short* w3t = (unsigned short*)(ws + OFF_W3T);
    float*          gts = (float*)(ws + OFF_G);
    unsigned short* h1  = (unsigned short*)(ws + OFF_H1);
    unsigned short* h2  = (unsigned short*)(ws + OFF_H2);
    unsigned short* h3  = (unsigned short*)(ws + OFF_H3);

    // weight transposes + fused gates/x-convert
    transpose_convert_kernel<<<dim3(D_IN / 32, H1 / 32, NEXP), dim3(32, 8), 0, stream>>>(W1, w1t, D_IN, H1);
    transpose_convert_kernel<<<dim3(H1 / 32, H2 / 32, NEXP), dim3(32, 8), 0, stream>>>(W2, w2t, H1, H2);
    transpose_convert_kernel<<<dim3(H2 / 32, H3 / 32, NEXP), dim3(32, 8), 0, stream>>>(W3, w3t, H2, H3);
    gates_convert_kernel<<<dim3(B_ROWS / 8), dim3(256), 0, stream>>>(x, gw, gts, xbf);

    // expert MLP layers
    gemm_bias_relu_kernel<<<dim3(B_ROWS / 128, H1 / 128, NEXP), dim3(256), 0, stream>>>(
        xbf, 0LL,
        w1t, (long long)H1 * D_IN,
        b1, (long long)H1,
        h1, (long long)B_ROWS * H1,
        B_ROWS, H1, D_IN);
    gemm_bias_relu_kernel<<<dim3(B_ROWS / 128, H2 / 128, NEXP), dim3(256), 0, stream>>>(
        h1, (long long)B_ROWS * H1,
        w2t, (long long)H2 * H1,
        b2, (long long)H2,
        h2, (long long)B_ROWS * H2,
        B_ROWS, H2, H1);
    gemm_bias_relu_kernel<<<dim3(B_ROWS / 128, H3 / 128, NEXP), dim3(256), 0, stream>>>(
        h2, (long long)B_ROWS * H2,
        w3t, (long long)H3 * H2,
        b3, (long long)H3,
        h3, (long long)B_ROWS * H3,
        B_ROWS, H3, H2);

    // gated combine
    combine_kernel<<<dim3(B_ROWS), dim3(256), 0, stream>>>(h3, gts, out);
}

// Round 7
// 453.983 us; speedup vs baseline: 1.5690x; 1.0004x over previous
//
#include <hip/hip_runtime.h>

// ---------------------------------------------------------------------------
// MMoE: B=8192, D_IN=1024, E=8, T=4, H1=1024, H2=512, H3=256
// R7: R6 GEMM core (tile 128x128, BK=64, 16x16x32 mfma, XOR-swizzled LDS,
// launch_bounds(256,4) -> 4 blocks/CU) + XCD-ownership block swizzle:
//   lin%8 -> XCD (round-robin heuristic). Each XCD owns expert e=lin&7;
//   within an XCD, n varies fastest, m outer. W[e] (<=2MB) stays L2-resident
//   and each A-tile is fetched once per XCD (kills the 4x h1 re-fetch that
//   made the L2-layer GEMM fetch-bound at ~133us).
// + vectorized weight transpose (64x64 tiles, 8B stores).
// fp32 gating fused with x->bf16 convert; fused bias+relu epilogues.
// ---------------------------------------------------------------------------

#define B_ROWS 8192
#define D_IN   1024
#define NEXP   8
#define NTASK  4
#define H1     1024
#define H2     512
#define H3     256

typedef __attribute__((ext_vector_type(8))) short bf16x8;
typedef __attribute__((ext_vector_type(4))) float f32x4;

__device__ __forceinline__ unsigned short f2bf(float f) {
    union { float f; unsigned int u; } x; x.f = f;
    unsigned int r = x.u + 0x7fffu + ((x.u >> 16) & 1u);  // RNE
    return (unsigned short)(r >> 16);
}
__device__ __forceinline__ float bf2f(unsigned short u) {
    union { unsigned int u; float f; } x; x.u = ((unsigned int)u) << 16;
    return x.f;
}

__device__ __forceinline__ void gload_lds16(const void* gptr, void* lptr) {
    __builtin_amdgcn_global_load_lds(
        (__attribute__((address_space(1))) void*)gptr,
        (__attribute__((address_space(3))) void*)lptr,
        16, 0, 0);
}

struct __align__(8) us4 { unsigned short x, y, z, w; };

// ---------------------------------------------------------------------------
// W [E][K][N] fp32 -> Wt [E][N][K] bf16. 64x64 tiles, block 256.
// Reads coalesced dwords; writes 8B us4 (16 threads x 8B = 128B/row-segment).
// LDS: 65-float row stride -> write-side reads are 2-way (free).
// ---------------------------------------------------------------------------
__global__ void transpose_convert_kernel(const float* __restrict__ W,
                                         unsigned short* __restrict__ Wt,
                                         int K, int N) {
    __shared__ float tile[64][65];
    const int e = blockIdx.z;
    const float* We = W + (size_t)e * K * N;
    unsigned short* Wte = Wt + (size_t)e * K * N;
    const int k0 = blockIdx.x * 64, n0 = blockIdx.y * 64;
    const int tid = threadIdx.x;
    const int tn = tid & 63;             // n within tile (read side)
    const int tk = tid >> 6;             // 0..3
#pragma unroll
    for (int i = 0; i < 16; ++i)
        tile[tk * 16 + i][tn] = We[(size_t)(k0 + tk * 16 + i) * N + n0 + tn];
    __syncthreads();
    const int wk = (tid & 15) * 4;       // k-chunk start (write side)
    const int wn = tid >> 4;             // 0..15
#pragma unroll
    for (int i = 0; i < 4; ++i) {
        const int n = wn + i * 16;
        us4 o;
        o.x = f2bf(tile[wk + 0][n]);
        o.y = f2bf(tile[wk + 1][n]);
        o.z = f2bf(tile[wk + 2][n]);
        o.w = f2bf(tile[wk + 3][n]);
        *(us4*)&Wte[(size_t)(n0 + n) * K + k0 + wk] = o;
    }
}

// ---------------------------------------------------------------------------
// GEMM: C[e] = relu(A[e] @ Bt[e]^T + bias[e]) ; all bf16, acc fp32
// A: [M,K] rm (per-expert stride Aes elems), Bt: [N,K] rm, C: [M,N] rm bf16
// block = 256 (4 waves, 2x2), tile 128x128, BK=64, single-buffered.
// XOR-swizzled LDS (chunk c of row r holds global chunk c^(r&7)): 0 conflicts.
// XCD-ownership swizzle: e = lin&7, slot = lin>>3; n = slot & (gy-1),
// m = slot >> log2(gy). Requires gridDim = (M/128, N/128, 8), all pow2.
// launch_bounds(256,4): 4 blocks/CU, 16 waves/CU.
// ---------------------------------------------------------------------------
__global__ __launch_bounds__(256, 4) void gemm_bias_relu_kernel(
    const unsigned short* __restrict__ A, long long Aes,
    const unsigned short* __restrict__ Bt, long long Bes,
    const float* __restrict__ bias, long long bias_es,
    unsigned short* __restrict__ C, long long Ces,
    int M, int N, int K) {
    __shared__ __align__(16) unsigned short sA[128 * 64];
    __shared__ __align__(16) unsigned short sB[128 * 64];

    const int tid  = threadIdx.x;
    const int lane = tid & 63;
    const int w    = tid >> 6;       // wave 0..3
    const int wr   = w >> 1, wc = w & 1;
    const int quad = lane >> 4, l15 = lane & 15;
    const int r8   = lane >> 3;      // staging row-in-octet 0..7
    const int c8   = lane & 7;       // staging 16B-chunk 0..7
    const int gchunk = c8 ^ r8;      // XOR-swizzled global chunk to fetch

    // XCD-ownership block swizzle
    const unsigned int gy   = gridDim.y;
    const unsigned int lin  = blockIdx.x + gridDim.x * (blockIdx.y + gy * blockIdx.z);
    const unsigned int e    = lin & 7;              // heuristic: lin%8 -> XCD
    const unsigned int slot = lin >> 3;
    const int gysh = __builtin_ctz(gy);
    const int n0 = (int)(slot & (gy - 1)) * 128;    // n fastest within XCD
    const int m0 = (int)(slot >> gysh) * 128;       // m outer

    A    += (size_t)e * Aes;
    Bt   += (size_t)e * Bes;
    bias += (size_t)e * bias_es;
    C    += (size_t)e * Ces;

    // staging: wave w covers A rows [w*32,w*32+32) and B rows [w*32,w*32+32)
    const unsigned short* Abase = A + (size_t)(m0 + w * 32 + r8) * K + gchunk * 8;
    const unsigned short* Bbase = Bt + (size_t)(n0 + w * 32 + r8) * K + gchunk * 8;
    unsigned short* sAw = &sA[(w * 32 + r8) * 64 + c8 * 8];
    unsigned short* sBw = &sB[(w * 32 + r8) * 64 + c8 * 8];

    f32x4 acc[4][4] = {};
    const int swz = l15 & 7;         // read-side XOR (row&7 of fragment rows)

    for (int k0 = 0; k0 < K; k0 += 64) {
#pragma unroll
        for (int q = 0; q < 4; ++q) {
            gload_lds16(Abase + (size_t)(q * 8) * K + k0, sAw + q * 8 * 64);
            gload_lds16(Bbase + (size_t)(q * 8) * K + k0, sBw + q * 8 * 64);
        }
        __syncthreads();

#pragma unroll
        for (int s = 0; s < 2; ++s) {
            const int cs = ((s * 4 + quad) ^ swz) * 8;  // swizzled k-chunk
            bf16x8 af[4], bfv[4];
#pragma unroll
            for (int i = 0; i < 4; ++i)
                af[i] = *(const bf16x8*)&sA[(wr * 64 + i * 16 + l15) * 64 + cs];
#pragma unroll
            for (int j = 0; j < 4; ++j)
                bfv[j] = *(const bf16x8*)&sB[(wc * 64 + j * 16 + l15) * 64 + cs];
#pragma unroll
            for (int i = 0; i < 4; ++i)
#pragma unroll
                for (int j = 0; j < 4; ++j)
                    acc[i][j] = __builtin_amdgcn_mfma_f32_16x16x32_bf16(
                        af[i], bfv[j], acc[i][j], 0, 0, 0);
        }
        __syncthreads();
    }

    // epilogue: C/D layout col=lane&15, row=quad*4+reg
#pragma unroll
    for (int j = 0; j < 4; ++j) {
        const int col = n0 + wc * 64 + j * 16 + l15;
        const float bv = bias[col];
#pragma unroll
        for (int i = 0; i < 4; ++i) {
#pragma unroll
            for (int r = 0; r < 4; ++r) {
                const int row = m0 + wr * 64 + i * 16 + quad * 4 + r;
                float v = acc[i][j][r] + bv;
                v = v > 0.f ? v : 0.f;
                C[(size_t)row * N + col] = f2bf(v);
            }
        }
    }
}

// ---------------------------------------------------------------------------
// gates + x->bf16 convert fused.
// block 256 = 8 rows x 32 outputs; also converts this block's 8 x-rows.
// ---------------------------------------------------------------------------
__global__ void gates_convert_kernel(const float* __restrict__ x,
                                     const float* __restrict__ gw,
                                     float* __restrict__ gates,
                                     unsigned short* __restrict__ xb) {
    const int tid = threadIdx.x;
    const size_t base = (size_t)blockIdx.x * 8192 + (size_t)tid * 32;
#pragma unroll
    for (int i = 0; i < 8; ++i) {
        float4 v = *(const float4*)&x[base + i * 4];
        us4 o4;
        o4.x = f2bf(v.x); o4.y = f2bf(v.y); o4.z = f2bf(v.z); o4.w = f2bf(v.w);
        ((us4*)xb)[base / 4 + i] = o4;
    }
    const int o = tid & 31;          // t*8 + e
    const int r = tid >> 5;          // 0..7
    const int b = blockIdx.x * 8 + r;
    const float* xr = x + (size_t)b * D_IN;
    float acc = 0.f;
    for (int k = 0; k < D_IN; k += 4) {
        float4 xv = *(const float4*)&xr[k];
        acc += xv.x * gw[(k + 0) * 32 + o];
        acc += xv.y * gw[(k + 1) * 32 + o];
        acc += xv.z * gw[(k + 2) * 32 + o];
        acc += xv.w * gw[(k + 3) * 32 + o];
    }
    float m = acc;
    m = fmaxf(m, __shfl_xor(m, 1));
    m = fmaxf(m, __shfl_xor(m, 2));
    m = fmaxf(m, __shfl_xor(m, 4));
    float ex = __expf(acc - m);
    float s = ex;
    s += __shfl_xor(s, 1);
    s += __shfl_xor(s, 2);
    s += __shfl_xor(s, 4);
    gates[(size_t)b * 32 + o] = ex / s;
}

// ---------------------------------------------------------------------------
// combine: out[t][b][d] = sum_e h3[e][b][d] * g[b][t*8+e]
// ---------------------------------------------------------------------------
__global__ void combine_kernel(const unsigned short* __restrict__ h3,
                               const float* __restrict__ gates,
                               float* __restrict__ out) {
    __shared__ float g[32];
    const int b = blockIdx.x;
    const int d = threadIdx.x;
    if (d < 32) g[d] = gates[(size_t)b * 32 + d];
    __syncthreads();
    float acc[NTASK] = {0.f, 0.f, 0.f, 0.f};
#pragma unroll
    for (int e = 0; e < NEXP; ++e) {
        const float h = bf2f(h3[((size_t)e * B_ROWS + b) * H3 + d]);
#pragma unroll
        for (int t = 0; t < NTASK; ++t) acc[t] += h * g[t * 8 + e];
    }
#pragma unroll
    for (int t = 0; t < NTASK; ++t)
        out[((size_t)t * B_ROWS + b) * H3 + d] = acc[t];
}

// ---------------------------------------------------------------------------
// workspace layout (bytes)
// ---------------------------------------------------------------------------
#define OFF_XBF 0u                          // 8192*1024*2      = 16,777,216
#define OFF_W1T 16777216u                   // 8*1024*1024*2    = 16,777,216
#define OFF_W2T 33554432u                   // 8*512*1024*2     =  8,388,608
#define OFF_W3T 41943040u                   // 8*256*512*2      =  2,097,152
#define OFF_G   44040192u                   // 8192*32*4        =  1,048,576
#define OFF_H1  45088768u                   // 8*8192*1024*2    = 134,217,728
#define OFF_H2  179306496u                  // 8*8192*512*2     = 67,108,864
#define OFF_H3  45088768u                   // aliases h1 (h1 dead after L2)
// total required: 246,415,360 bytes

extern "C" void kernel_launch(void* const* d_in, const int* in_sizes, int n_in,
                              void* d_out, int out_size, void* d_ws, size_t ws_size,
                              hipStream_t stream) {
    const float* x  = (const float*)d_in[0];
    const float* W1 = (const float*)d_in[1];
    const float* b1 = (const float*)d_in[2];
    const float* W2 = (const float*)d_in[3];
    const float* b2 = (const float*)d_in[4];
    const float* W3 = (const float*)d_in[5];
    const float* b3 = (const float*)d_in[6];
    const float* gw = (const float*)d_in[7];
    float* out = (float*)d_out;
    char* ws = (char*)d_ws;

    unsigned short* xbf = (unsigned short*)(ws + OFF_XBF);
    unsigned short* w1t = (unsigned short*)(ws + OFF_W1T);
    unsigned short* w2t = (unsigned short*)(ws + OFF_W2T);
    unsigned short* w3t = (unsigned short*)(ws + OFF_W3T);
    float*          gts = (float*)(ws + OFF_G);
    unsigned short* h1  = (unsigned short*)(ws + OFF_H1);
    unsigned short* h2  = (unsigned short*)(ws + OFF_H2);
    unsigned short* h3  = (unsigned short*)(ws + OFF_H3);

    // weight transposes + fused gates/x-convert
    transpose_convert_kernel<<<dim3(D_IN / 64, H1 / 64, NEXP), dim3(256), 0, stream>>>(W1, w1t, D_IN, H1);
    transpose_convert_kernel<<<dim3(H1 / 64, H2 / 64, NEXP), dim3(256), 0, stream>>>(W2, w2t, H1, H2);
    transpose_convert_kernel<<<dim3(H2 / 64, H3 / 64, NEXP), dim3(256), 0, stream>>>(W3, w3t, H2, H3);
    gates_convert_kernel<<<dim3(B_ROWS / 8), dim3(256), 0, stream>>>(x, gw, gts, xbf);

    // expert MLP layers
    gemm_bias_relu_kernel<<<dim3(B_ROWS / 128, H1 / 128, NEXP), dim3(256), 0, stream>>>(
        xbf, 0LL,
        w1t, (long long)H1 * D_IN,
        b1, (long long)H1,
        h1, (long long)B_ROWS * H1,
        B_ROWS, H1, D_IN);
    gemm_bias_relu_kernel<<<dim3(B_ROWS / 128, H2 / 128, NEXP), dim3(256), 0, stream>>>(
        h1, (long long)B_ROWS * H1,
        w2t, (long long)H2 * H1,
        b2, (long long)H2,
        h2, (long long)B_ROWS * H2,
        B_ROWS, H2, H1);
    gemm_bias_relu_kernel<<<dim3(B_ROWS / 128, H3 / 128, NEXP), dim3(256), 0, stream>>>(
        h2, (long long)B_ROWS * H2,
        w3t, (long long)H3 * H2,
        b3, (long long)H3,
        h3, (long long)B_ROWS * H3,
        B_ROWS, H3, H2);

    // gated combine
    combine_kernel<<<dim3(B_ROWS), dim3(256), 0, stream>>>(h3, gts, out);
}